// Round 15
// baseline (253.139 us; speedup 1.0000x reference)
//
#include <hip/hip_runtime.h>
#include <math.h>

typedef unsigned short u16;
typedef unsigned int u32;
typedef short bf16x8 __attribute__((ext_vector_type(8)));
typedef float f32x4 __attribute__((ext_vector_type(4)));
typedef _Float16 f16x4 __attribute__((ext_vector_type(4)));

#define TT 5
#define HEADS 6
#define HD 32
#define DIM 192
#define NWIN 320              // tokens per window = T*8*8
#define LTOK (TT*64*64)       // 20480
#define BATCH 2
#define MROWS (BATCH*LTOK)    // 40960
#define QSCALE 0.17677669529663687f   // 1/sqrt(32)
#define LOG2E 1.4426950408889634f
#define QSCALE2 (QSCALE * LOG2E)
#define MASK2 (-100.0f * LOG2E)       // -144.2695: 2^x -> 0
#define CVT_BLOCKS 1728               // 12*DIM*DIM/256

__device__ __forceinline__ u16 f2bf(float f) {
    u32 u = __float_as_uint(f);
    u32 r = (u + 0x7FFFu + ((u >> 16) & 1u)) >> 16;
    return (u16)r;
}
__device__ __forceinline__ float bflo(u32 u) { return __uint_as_float(u << 16); }
__device__ __forceinline__ float bfhi(u32 u) { return __uint_as_float(u & 0xFFFF0000u); }
__device__ __forceinline__ u32 pkh(float a, float b) {
    auto h = __builtin_amdgcn_cvt_pkrtz(a, b);
    return __builtin_bit_cast(u32, h);
}
#if __has_builtin(__builtin_amdgcn_exp2f)
__device__ __forceinline__ float ex2(float x) { return __builtin_amdgcn_exp2f(x); }
#else
__device__ __forceinline__ float ex2(float x) {
    float r; asm("v_exp_f32 %0, %1" : "=v"(r) : "v"(x)); return r;
}
#endif

// ---- prep: weight cvt (blocks 0..1727) + LN1 (remaining blocks) ----------
__global__ __launch_bounds__(256) void prep_kernel(
    const float* __restrict__ x, const float* __restrict__ g,
    const float* __restrict__ b, u16* __restrict__ out,
    const float* __restrict__ wa, const float* __restrict__ wb,
    const float* __restrict__ wc, const float* __restrict__ wd,
    u16* __restrict__ oa, u16* __restrict__ ob,
    u16* __restrict__ oc, u16* __restrict__ od)
{
    if (blockIdx.x < CVT_BLOCKS) {
        int i = blockIdx.x * 256 + threadIdx.x;
        if (i < 110592)       oa[i]          = f2bf(wa[i]);           // qkv_w
        else if (i < 147456)  ob[i - 110592] = f2bf(wb[i - 110592]);  // proj_w
        else if (i < 294912)  oc[i - 147456] = f2bf(wc[i - 147456]);  // fc1_w
        else                  od[i - 294912] = f2bf(wd[i - 294912]);  // fc2_w
        return;
    }
    int tok  = (blockIdx.x - CVT_BLOCKS) * 4 + (threadIdx.x >> 6);
    int lane = threadIdx.x & 63;
    const float* xr = x + (size_t)tok * DIM;
    float v0 = xr[lane], v1 = xr[lane + 64], v2 = xr[lane + 128];
    float s = v0 + v1 + v2;
    #pragma unroll
    for (int off = 32; off; off >>= 1) s += __shfl_xor(s, off, 64);
    float mu = s * (1.0f / 192.0f);
    float d0 = v0 - mu, d1 = v1 - mu, d2 = v2 - mu;
    float vs = d0 * d0 + d1 * d1 + d2 * d2;
    #pragma unroll
    for (int off = 32; off; off >>= 1) vs += __shfl_xor(vs, off, 64);
    float rstd = rsqrtf(vs * (1.0f / 192.0f) + 1e-5f);
    u16* orow = out + (size_t)tok * DIM;
    orow[lane]       = f2bf(d0 * rstd * g[lane]       + b[lane]);
    orow[lane + 64]  = f2bf(d1 * rstd * g[lane + 64]  + b[lane + 64]);
    orow[lane + 128] = f2bf(d2 * rstd * g[lane + 128] + b[lane + 128]);
}

// ---------------- bf16 MFMA GEMM: C = A(MxK) @ W(NxK)^T + bias ------------
// r4 structure (single-buffer staged loop + XCD swizzle). History: r5 dbuf /
// r7 direct-A / r8 hoist / r11 fused-MLP all regressed; r13: BM=64 on
// grid-filled GEMMs per-se neutral. Config per r12 best: qkv/fc1 128, fc2 64.
template<int EPI, int BM>
__global__ __launch_bounds__(256) void mfma_gemm(
    const u16* __restrict__ A, const u16* __restrict__ W,
    const float* __restrict__ bias, void* __restrict__ outp,
    const float* __restrict__ xin, int N, int K)
{
    constexpr int WR = BM / 64;     // 16-row tiles per wave
    constexpr int NA = BM / 32;     // A-stage chunks per K-step
    __shared__ u16 As[BM * 64];
    __shared__ u16 Bs[64 * 64];
    const int tid  = threadIdx.x;
    const int lane = tid & 63, wv = tid >> 6;
    const int ln16 = lane & 15, quad = lane >> 4;

    const int flat  = blockIdx.y * gridDim.x + blockIdx.x;
    const int cpx   = (gridDim.x * gridDim.y) >> 3;
    const int nf    = (flat & 7) * cpx + (flat >> 3);
    const int bn    = nf % gridDim.x;
    const int bm    = nf / gridDim.x;

    const int srow = lane >> 3;
    const int sxor = (lane & 7) ^ srow;
    const int acol = sxor * 8;

    f32x4 acc[WR][4] = {};

    for (int k0 = 0; k0 < K; k0 += 64) {
        __syncthreads();
        #pragma unroll
        for (int a = 0; a < NA; ++a) {
            const u16* g = A + (size_t)(bm * BM + a * 32 + wv * 8 + srow) * K + k0 + acol;
            __builtin_amdgcn_global_load_lds(
                (const __attribute__((address_space(1))) u32*)g,
                (__attribute__((address_space(3))) u32*)((char*)As + a * 4096 + wv * 1024),
                16, 0, 0);
        }
        #pragma unroll
        for (int bb = 0; bb < 2; ++bb) {
            const u16* g = W + (size_t)(bn * 64 + bb * 32 + wv * 8 + srow) * K + k0 + acol;
            __builtin_amdgcn_global_load_lds(
                (const __attribute__((address_space(1))) u32*)g,
                (__attribute__((address_space(3))) u32*)((char*)Bs + bb * 4096 + wv * 1024),
                16, 0, 0);
        }
        __syncthreads();
        #pragma unroll
        for (int s = 0; s < 2; ++s) {
            bf16x8 af[WR], bf[4];
            #pragma unroll
            for (int i = 0; i < WR; ++i) {
                int r = wv * (16 * WR) + i * 16 + ln16;
                int slot = (s * 4 + quad) ^ (r & 7);
                af[i] = *(const bf16x8*)((const char*)As + r * 128 + slot * 16);
            }
            #pragma unroll
            for (int j = 0; j < 4; ++j) {
                int r = j * 16 + ln16;
                int slot = (s * 4 + quad) ^ (r & 7);
                bf[j] = *(const bf16x8*)((const char*)Bs + r * 128 + slot * 16);
            }
            #pragma unroll
            for (int i = 0; i < WR; ++i)
                #pragma unroll
                for (int j = 0; j < 4; ++j)
                    acc[i][j] = __builtin_amdgcn_mfma_f32_16x16x32_bf16(
                        af[i], bf[j], acc[i][j], 0, 0, 0);
        }
    }

    #pragma unroll
    for (int i = 0; i < WR; ++i) {
        int gr0 = bm * BM + wv * (16 * WR) + i * 16 + quad * 4;
        #pragma unroll
        for (int j = 0; j < 4; ++j) {
            int gc = bn * 64 + j * 16 + ln16;
            float bv = bias[gc];
            #pragma unroll
            for (int rr = 0; rr < 4; ++rr) {
                int gr = gr0 + rr;
                float val = acc[i][j][rr] + bv;
                if (EPI == 0) {
                    ((u16*)outp)[(size_t)gr * N + gc] = f2bf(val);
                } else if (EPI == 1) {
                    float gl = val * 0.5f * (1.0f + erff(val * 0.70710678118654752f));
                    ((u16*)outp)[(size_t)gr * N + gc] = f2bf(gl);
                } else {
                    ((float*)outp)[(size_t)gr * N + gc] += val;
                }
            }
        }
    }
}

// ---- proj GEMM (full 192-col rows) + residual + FUSED LN2 epilogue -------
// r12-verified: deletes the LN2 dispatch. Single-pass E[x2]-E[x]2 row stats
// via 12-reg partials + 4 shfl_xor; writes out (f32) and h_buf (bf16 LN2).
__global__ __launch_bounds__(256) void proj_ln_kernel(
    const u16* __restrict__ A,       // att_buf bf16 [MROWS][192]
    const u16* __restrict__ W,       // proj_w bf16 [192][192]
    const float* __restrict__ bias,  // proj_b
    const float* __restrict__ xin,   // x f32
    float* __restrict__ out,         // x + attnproj (f32)
    const float* __restrict__ g2, const float* __restrict__ b2,
    u16* __restrict__ hout)          // h_buf bf16 = LN2(out)
{
    __shared__ u16 As[64 * 64];      // 8KB
    __shared__ u16 Bs[192 * 64];     // 24KB
    const int tid  = threadIdx.x;
    const int lane = tid & 63, wv = tid >> 6;
    const int ln16 = lane & 15, quad = lane >> 4;
    const int srow = lane >> 3;
    const int acol = ((lane & 7) ^ srow) * 8;

    const int flat = blockIdx.x;                 // grid 640, %8==0
    const int bm   = (flat & 7) * (gridDim.x >> 3) + (flat >> 3);

    f32x4 acc[12] = {};

    for (int k0 = 0; k0 < DIM; k0 += 64) {
        __syncthreads();
        #pragma unroll
        for (int a = 0; a < 2; ++a) {
            const u16* g = A + (size_t)(bm * 64 + a * 32 + wv * 8 + srow) * DIM + k0 + acol;
            __builtin_amdgcn_global_load_lds(
                (const __attribute__((address_space(1))) u32*)g,
                (__attribute__((address_space(3))) u32*)((char*)As + a * 4096 + wv * 1024),
                16, 0, 0);
        }
        #pragma unroll
        for (int bb = 0; bb < 6; ++bb) {
            const u16* g = W + (size_t)(bb * 32 + wv * 8 + srow) * DIM + k0 + acol;
            __builtin_amdgcn_global_load_lds(
                (const __attribute__((address_space(1))) u32*)g,
                (__attribute__((address_space(3))) u32*)((char*)Bs + bb * 4096 + wv * 1024),
                16, 0, 0);
        }
        __syncthreads();
        #pragma unroll
        for (int s = 0; s < 2; ++s) {
            int ra = wv * 16 + ln16;
            int slota = (s * 4 + quad) ^ (ra & 7);
            bf16x8 af = *(const bf16x8*)((const char*)As + ra * 128 + slota * 16);
            #pragma unroll
            for (int nt = 0; nt < 12; ++nt) {
                int r = nt * 16 + ln16;
                int slot = (s * 4 + quad) ^ (r & 7);
                bf16x8 bf = *(const bf16x8*)((const char*)Bs + r * 128 + slot * 16);
                acc[nt] = __builtin_amdgcn_mfma_f32_16x16x32_bf16(af, bf, acc[nt], 0, 0, 0);
            }
        }
    }

    const int gr0 = bm * 64 + wv * 16 + quad * 4;
    float s1[4] = {}, s2[4] = {};
    #pragma unroll
    for (int nt = 0; nt < 12; ++nt) {
        int gc = nt * 16 + ln16;
        float bv = bias[gc];
        #pragma unroll
        for (int rr = 0; rr < 4; ++rr) {
            size_t dst = (size_t)(gr0 + rr) * DIM + gc;
            float ov = xin[dst] + acc[nt][rr] + bv;
            out[dst] = ov;
            s1[rr] += ov;
            s2[rr] += ov * ov;
        }
    }
    #pragma unroll
    for (int rr = 0; rr < 4; ++rr) {
        #pragma unroll
        for (int off = 8; off; off >>= 1) {
            s1[rr] += __shfl_xor(s1[rr], off, 64);
            s2[rr] += __shfl_xor(s2[rr], off, 64);
        }
    }
    float mu[4], rstd[4];
    #pragma unroll
    for (int rr = 0; rr < 4; ++rr) {
        mu[rr] = s1[rr] * (1.0f / 192.0f);
        float var = s2[rr] * (1.0f / 192.0f) - mu[rr] * mu[rr];
        rstd[rr] = rsqrtf(var + 1e-5f);
    }
    #pragma unroll
    for (int nt = 0; nt < 12; ++nt) {
        int gc = nt * 16 + ln16;
        float bv = bias[gc];
        float gg = g2[gc], bb = b2[gc];
        #pragma unroll
        for (int rr = 0; rr < 4; ++rr) {
            size_t dst = (size_t)(gr0 + rr) * DIM + gc;
            float ov = xin[dst] + acc[nt][rr] + bv;
            hout[dst] = f2bf((ov - mu[rr]) * rstd[rr] * gg + bb);
        }
    }
}

// ---------------- MFMA flash attention: block = (window, head) ------------
// r4 softmax structure (static-max exp2, window-order store). r15 change:
// NO K LDS staging -- K is consumed as row-major direct fragments (the
// exact layout it has in qkv_buf), and the per-block K working set
// (320x64B = 20KB) fits L1, so staging it was pure overhead (m169 /
// Common-mistake #7). Per-chunk window-gather address computed in-loop
// (~28 VALU/chunk). LDS 48.1 -> ~22.4KB => blocks/CU 3 -> 6 (30 waves/CU),
// doubling TLP for this latency-bound kernel. setprio removed (r14: null,
// +4 VGPR). VGPR must stay modest; LDS no longer the occupancy cap.
__global__ __launch_bounds__(320) void attn_kernel(
    const u16* __restrict__ qkv, const float* __restrict__ table,
    u16* __restrict__ attout)
{
    const int head = blockIdx.x % HEADS;
    const int b_   = blockIdx.x / HEADS;
    const int b = b_ >> 6, hb = (b_ >> 3) & 7, wb = b_ & 7;
    const int tid = threadIdx.x;
    const int lane = tid & 63, wv = tid >> 6;
    const int ln16 = lane & 15, quad = lane >> 4;

    __shared__ u16 Vt[32 * 328];     // f16 transposed, row pad 328 (~21KB)
    __shared__ u16 meta[320];        // off | (region<<8) per key token
    __shared__ float tbl[188];       // bias table pre-scaled by log2(e)

    // ---- staging: thread tid = window token n (V transpose + meta + tbl) --
    {
        int n = tid;
        int t1 = n >> 6, r1 = (n >> 3) & 7, c1 = n & 7;
        int h1 = hb * 8 + r1, w1 = wb * 8 + c1;
        int l1 = t1 * 4096 + ((h1 + 4) & 63) * 64 + ((w1 + 4) & 63);
        const u16* src = qkv + ((size_t)b * LTOK + l1) * (3 * DIM) + head * HD;
        const uint4* v4 = (const uint4*)(src + 2 * DIM);
        #pragma unroll
        for (int i = 0; i < 4; ++i) {
            uint4 u = v4[i];
            u32 ws[4] = {u.x, u.y, u.z, u.w};
            #pragma unroll
            for (int j = 0; j < 4; ++j) {
                u32 hb2 = pkh(bflo(ws[j]), bfhi(ws[j]));
                int d = i * 8 + j * 2;
                Vt[d * 328 + n]       = (u16)(hb2 & 0xFFFF);
                Vt[(d + 1) * 328 + n] = (u16)(hb2 >> 16);
            }
        }
        int off = (7 - t1) * 15 + 7 - r1 - c1;
        int rh = h1 < 56 ? 0 : (h1 < 60 ? 1 : 2);
        int rw = w1 < 56 ? 0 : (w1 < 60 ? 1 : 2);
        meta[n] = (u16)(off | ((rh * 3 + rw) << 8));
        if (n < 187) tbl[n] = table[n * HEADS + head] * LOG2E;
    }

    // ---- per-wave Q setup: 4 q-tiles of 16 rows ---------------------------
    bf16x8 qf[4];
    int basen[4], myreg[4];
    #pragma unroll
    for (int qt = 0; qt < 4; ++qt) {
        int nq = wv * 64 + qt * 16 + ln16;
        int t1 = nq >> 6, r1 = (nq >> 3) & 7, c1 = nq & 7;
        int h1 = hb * 8 + r1, w1 = wb * 8 + c1;
        int l1 = t1 * 4096 + ((h1 + 4) & 63) * 64 + ((w1 + 4) & 63);
        qf[qt] = *(const bf16x8*)(qkv + ((size_t)b * LTOK + l1) * (3 * DIM)
                                  + head * HD + quad * 8);
        basen[qt] = t1 * 15 + r1 + c1;
        int rh = h1 < 56 ? 0 : (h1 < 60 ? 1 : 2);
        int rw = w1 < 56 ? 0 : (w1 < 60 ? 1 : 2);
        myreg[qt] = rh * 3 + rw;
    }

    __syncthreads();

    // loop-invariant bases for in-loop K row gather
    const int hb4 = hb * 8 + 4, wb4 = wb * 8 + 4;
    const u16* kbase = qkv + (size_t)b * LTOK * (3 * DIM) + DIM + head * HD + quad * 8;

    f32x4 o[4][2] = {};          // [qtile][d-half]: O^T rows=d(quad*4+r), col=qrow(ln16)
    float l_[4] = {};
    const f32x4 zero = {};

    #pragma unroll 1
    for (int c = 0; c < 10; ++c) {
        int kb = c * 32;
        // direct global K fragments (window-gathered rows, L1-hot 20KB set)
        int n0 = kb + ln16;
        int l0 = ((n0 >> 6) << 12) + (((hb4 + ((n0 >> 3) & 7)) & 63) << 6)
               + ((wb4 + (n0 & 7)) & 63);
        int n1 = n0 + 16;
        int l1i = ((n1 >> 6) << 12) + (((hb4 + ((n1 >> 3) & 7)) & 63) << 6)
                + ((wb4 + (n1 & 7)) & 63);
        bf16x8 af0 = *(const bf16x8*)(kbase + (size_t)l0 * (3 * DIM));
        bf16x8 af1 = *(const bf16x8*)(kbase + (size_t)l1i * (3 * DIM));
        f16x4 va[2][2];
        #pragma unroll
        for (int dt = 0; dt < 2; ++dt)
            #pragma unroll
            for (int kt = 0; kt < 2; ++kt)
                va[dt][kt] = *(const f16x4*)(Vt + (dt * 16 + ln16) * 328
                                             + kb + kt * 16 + quad * 4);
        ushort4 m4a = *(const ushort4*)(meta + kb + quad * 4);
        ushort4 m4b = *(const ushort4*)(meta + kb + 16 + quad * 4);
        u16 mta[4] = {m4a.x, m4a.y, m4a.z, m4a.w};
        u16 mtb[4] = {m4b.x, m4b.y, m4b.z, m4b.w};

        #pragma unroll
        for (int qt = 0; qt < 4; ++qt) {
            f32x4 s0 = __builtin_amdgcn_mfma_f32_16x16x32_bf16(af0, qf[qt], zero, 0, 0, 0);
            f32x4 s1 = __builtin_amdgcn_mfma_f32_16x16x32_bf16(af1, qf[qt], zero, 0, 0, 0);
            float p[8];
            #pragma unroll
            for (int r = 0; r < 4; ++r) {
                int ma = mta[r], mb = mtb[r];
                float va0 = fmaf(s0[r], QSCALE2, tbl[basen[qt] + (ma & 0xFF)]);
                float vb0 = fmaf(s1[r], QSCALE2, tbl[basen[qt] + (mb & 0xFF)]);
                p[r]     = va0 + (((ma >> 8) == myreg[qt]) ? 0.0f : MASK2);
                p[4 + r] = vb0 + (((mb >> 8) == myreg[qt]) ? 0.0f : MASK2);
            }
            float ls = 0.0f;
            #pragma unroll
            for (int j = 0; j < 8; ++j) { p[j] = ex2(p[j]); ls += p[j]; }
            l_[qt] += ls;
            uint2 pk0 = { pkh(p[0], p[1]), pkh(p[2], p[3]) };
            uint2 pk1 = { pkh(p[4], p[5]), pkh(p[6], p[7]) };
            f16x4 pf0 = __builtin_bit_cast(f16x4, pk0);
            f16x4 pf1 = __builtin_bit_cast(f16x4, pk1);
            #pragma unroll
            for (int dt = 0; dt < 2; ++dt) {
                o[qt][dt] = __builtin_amdgcn_mfma_f32_16x16x16f16(va[dt][0], pf0, o[qt][dt], 0, 0, 0);
                o[qt][dt] = __builtin_amdgcn_mfma_f32_16x16x16f16(va[dt][1], pf1, o[qt][dt], 0, 0, 0);
            }
        }
    }

    // ---- epilogue: normalize, pack bf16, store O (token-major) ------------
    #pragma unroll
    for (int qt = 0; qt < 4; ++qt) {
        float lt = l_[qt];
        lt += __shfl_xor(lt, 16, 64);
        lt += __shfl_xor(lt, 32, 64);
        float inv = 1.0f / lt;
        int nq = wv * 64 + qt * 16 + ln16;
        u16* dst = attout + ((size_t)(b_ * NWIN + nq)) * DIM + head * HD + quad * 4;
        #pragma unroll
        for (int dt = 0; dt < 2; ++dt) {
            u32 w0 = (u32)f2bf(o[qt][dt][0] * inv) | ((u32)f2bf(o[qt][dt][1] * inv) << 16);
            u32 w1 = (u32)f2bf(o[qt][dt][2] * inv) | ((u32)f2bf(o[qt][dt][3] * inv) << 16);
            uint2 st = {w0, w1};
            *(uint2*)(dst + dt * 16) = st;
        }
    }
}

// ---------------------------------------------------------------------------
extern "C" void kernel_launch(void* const* d_in, const int* in_sizes, int n_in,
                              void* d_out, int out_size, void* d_ws, size_t ws_size,
                              hipStream_t stream)
{
    (void)in_sizes; (void)n_in; (void)out_size; (void)ws_size;
    const float* x      = (const float*)d_in[0];
    const float* ln1_g  = (const float*)d_in[1];
    const float* ln1_b  = (const float*)d_in[2];
    const float* qkv_w  = (const float*)d_in[3];
    const float* qkv_b  = (const float*)d_in[4];
    const float* table  = (const float*)d_in[5];
    const float* proj_w = (const float*)d_in[6];
    const float* proj_b = (const float*)d_in[7];
    const float* ln2_g  = (const float*)d_in[8];
    const float* ln2_b  = (const float*)d_in[9];
    const float* fc1_w  = (const float*)d_in[10];
    const float* fc1_b  = (const float*)d_in[11];
    const float* fc2_w  = (const float*)d_in[12];
    const float* fc2_b  = (const float*)d_in[13];
    float* out = (float*)d_out;

    u16* wsu     = (u16*)d_ws;
    u16* h_buf   = wsu;
    u16* qkv_buf = wsu + (size_t)MROWS * DIM;
    u16* att_buf = wsu + (size_t)MROWS * (4 * DIM);
    u16* fc1_buf = wsu + (size_t)MROWS * DIM;
    u16* wq = wsu + (size_t)MROWS * (5 * DIM);
    u16* wp = wq + 3 * DIM * DIM;
    u16* w1 = wp + DIM * DIM;
    u16* w2 = w1 + 4 * DIM * DIM;

    prep_kernel<<<CVT_BLOCKS + MROWS / 4, 256, 0, stream>>>(
        x, ln1_g, ln1_b, h_buf,
        qkv_w, proj_w, fc1_w, fc2_w, wq, wp, w1, w2);

    mfma_gemm<0, 128><<<dim3(3 * DIM / 64, MROWS / 128), 256, 0, stream>>>(
        h_buf, wq, qkv_b, qkv_buf, nullptr, 3 * DIM, DIM);
    attn_kernel<<<128 * HEADS, 320, 0, stream>>>(qkv_buf, table, att_buf);
    proj_ln_kernel<<<MROWS / 64, 256, 0, stream>>>(
        att_buf, wp, proj_b, x, out, ln2_g, ln2_b, h_buf);
    mfma_gemm<1, 128><<<dim3(4 * DIM / 64, MROWS / 128), 256, 0, stream>>>(
        h_buf, w1, fc1_b, fc1_buf, nullptr, 4 * DIM, DIM);
    mfma_gemm<3, 64><<<dim3(DIM / 64, MROWS / 64), 256, 0, stream>>>(
        fc1_buf, w2, fc2_b, out, nullptr, DIM, 4 * DIM);
}

// Round 16
// 247.207 us; speedup vs baseline: 1.0240x; 1.0240x over previous
//
#include <hip/hip_runtime.h>
#include <math.h>

typedef unsigned short u16;
typedef unsigned int u32;
typedef short bf16x8 __attribute__((ext_vector_type(8)));
typedef float f32x4 __attribute__((ext_vector_type(4)));
typedef _Float16 f16x4 __attribute__((ext_vector_type(4)));

#define TT 5
#define HEADS 6
#define HD 32
#define DIM 192
#define NWIN 320              // tokens per window = T*8*8
#define LTOK (TT*64*64)       // 20480
#define BATCH 2
#define MROWS (BATCH*LTOK)    // 40960
#define QSCALE 0.17677669529663687f   // 1/sqrt(32)
#define LOG2E 1.4426950408889634f
#define QSCALE2 (QSCALE * LOG2E)
#define MASK2 (-100.0f * LOG2E)       // -144.2695: 2^x -> 0
#define CVT_BLOCKS 1728               // 12*DIM*DIM/256

__device__ __forceinline__ u16 f2bf(float f) {
    u32 u = __float_as_uint(f);
    u32 r = (u + 0x7FFFu + ((u >> 16) & 1u)) >> 16;
    return (u16)r;
}
__device__ __forceinline__ float bflo(u32 u) { return __uint_as_float(u << 16); }
__device__ __forceinline__ float bfhi(u32 u) { return __uint_as_float(u & 0xFFFF0000u); }
__device__ __forceinline__ u32 pkh(float a, float b) {
    auto h = __builtin_amdgcn_cvt_pkrtz(a, b);
    return __builtin_bit_cast(u32, h);
}
#if __has_builtin(__builtin_amdgcn_exp2f)
__device__ __forceinline__ float ex2(float x) { return __builtin_amdgcn_exp2f(x); }
#else
__device__ __forceinline__ float ex2(float x) {
    float r; asm("v_exp_f32 %0, %1" : "=v"(r) : "v"(x)); return r;
}
#endif

// ---- prep: weight cvt (blocks 0..1727) + LN1 (remaining blocks) ----------
__global__ __launch_bounds__(256) void prep_kernel(
    const float* __restrict__ x, const float* __restrict__ g,
    const float* __restrict__ b, u16* __restrict__ out,
    const float* __restrict__ wa, const float* __restrict__ wb,
    const float* __restrict__ wc, const float* __restrict__ wd,
    u16* __restrict__ oa, u16* __restrict__ ob,
    u16* __restrict__ oc, u16* __restrict__ od)
{
    if (blockIdx.x < CVT_BLOCKS) {
        int i = blockIdx.x * 256 + threadIdx.x;
        if (i < 110592)       oa[i]          = f2bf(wa[i]);           // qkv_w
        else if (i < 147456)  ob[i - 110592] = f2bf(wb[i - 110592]);  // proj_w
        else if (i < 294912)  oc[i - 147456] = f2bf(wc[i - 147456]);  // fc1_w
        else                  od[i - 294912] = f2bf(wd[i - 294912]);  // fc2_w
        return;
    }
    int tok  = (blockIdx.x - CVT_BLOCKS) * 4 + (threadIdx.x >> 6);
    int lane = threadIdx.x & 63;
    const float* xr = x + (size_t)tok * DIM;
    float v0 = xr[lane], v1 = xr[lane + 64], v2 = xr[lane + 128];
    float s = v0 + v1 + v2;
    #pragma unroll
    for (int off = 32; off; off >>= 1) s += __shfl_xor(s, off, 64);
    float mu = s * (1.0f / 192.0f);
    float d0 = v0 - mu, d1 = v1 - mu, d2 = v2 - mu;
    float vs = d0 * d0 + d1 * d1 + d2 * d2;
    #pragma unroll
    for (int off = 32; off; off >>= 1) vs += __shfl_xor(vs, off, 64);
    float rstd = rsqrtf(vs * (1.0f / 192.0f) + 1e-5f);
    u16* orow = out + (size_t)tok * DIM;
    orow[lane]       = f2bf(d0 * rstd * g[lane]       + b[lane]);
    orow[lane + 64]  = f2bf(d1 * rstd * g[lane + 64]  + b[lane + 64]);
    orow[lane + 128] = f2bf(d2 * rstd * g[lane + 128] + b[lane + 128]);
}

// ---------------- bf16 MFMA GEMM: C = A(MxK) @ W(NxK)^T + bias ------------
// r4 structure (single-buffer staged loop + XCD swizzle). History: r5 dbuf /
// r7 direct-A / r8 hoist / r11 fused-MLP all regressed; r13: BM=64 on
// grid-filled GEMMs per-se neutral. Config per r12 best: qkv/fc1 128, fc2 64.
template<int EPI, int BM>
__global__ __launch_bounds__(256) void mfma_gemm(
    const u16* __restrict__ A, const u16* __restrict__ W,
    const float* __restrict__ bias, void* __restrict__ outp,
    const float* __restrict__ xin, int N, int K)
{
    constexpr int WR = BM / 64;     // 16-row tiles per wave
    constexpr int NA = BM / 32;     // A-stage chunks per K-step
    __shared__ u16 As[BM * 64];
    __shared__ u16 Bs[64 * 64];
    const int tid  = threadIdx.x;
    const int lane = tid & 63, wv = tid >> 6;
    const int ln16 = lane & 15, quad = lane >> 4;

    const int flat  = blockIdx.y * gridDim.x + blockIdx.x;
    const int cpx   = (gridDim.x * gridDim.y) >> 3;
    const int nf    = (flat & 7) * cpx + (flat >> 3);
    const int bn    = nf % gridDim.x;
    const int bm    = nf / gridDim.x;

    const int srow = lane >> 3;
    const int sxor = (lane & 7) ^ srow;
    const int acol = sxor * 8;

    f32x4 acc[WR][4] = {};

    for (int k0 = 0; k0 < K; k0 += 64) {
        __syncthreads();
        #pragma unroll
        for (int a = 0; a < NA; ++a) {
            const u16* g = A + (size_t)(bm * BM + a * 32 + wv * 8 + srow) * K + k0 + acol;
            __builtin_amdgcn_global_load_lds(
                (const __attribute__((address_space(1))) u32*)g,
                (__attribute__((address_space(3))) u32*)((char*)As + a * 4096 + wv * 1024),
                16, 0, 0);
        }
        #pragma unroll
        for (int bb = 0; bb < 2; ++bb) {
            const u16* g = W + (size_t)(bn * 64 + bb * 32 + wv * 8 + srow) * K + k0 + acol;
            __builtin_amdgcn_global_load_lds(
                (const __attribute__((address_space(1))) u32*)g,
                (__attribute__((address_space(3))) u32*)((char*)Bs + bb * 4096 + wv * 1024),
                16, 0, 0);
        }
        __syncthreads();
        #pragma unroll
        for (int s = 0; s < 2; ++s) {
            bf16x8 af[WR], bf[4];
            #pragma unroll
            for (int i = 0; i < WR; ++i) {
                int r = wv * (16 * WR) + i * 16 + ln16;
                int slot = (s * 4 + quad) ^ (r & 7);
                af[i] = *(const bf16x8*)((const char*)As + r * 128 + slot * 16);
            }
            #pragma unroll
            for (int j = 0; j < 4; ++j) {
                int r = j * 16 + ln16;
                int slot = (s * 4 + quad) ^ (r & 7);
                bf[j] = *(const bf16x8*)((const char*)Bs + r * 128 + slot * 16);
            }
            #pragma unroll
            for (int i = 0; i < WR; ++i)
                #pragma unroll
                for (int j = 0; j < 4; ++j)
                    acc[i][j] = __builtin_amdgcn_mfma_f32_16x16x32_bf16(
                        af[i], bf[j], acc[i][j], 0, 0, 0);
        }
    }

    #pragma unroll
    for (int i = 0; i < WR; ++i) {
        int gr0 = bm * BM + wv * (16 * WR) + i * 16 + quad * 4;
        #pragma unroll
        for (int j = 0; j < 4; ++j) {
            int gc = bn * 64 + j * 16 + ln16;
            float bv = bias[gc];
            #pragma unroll
            for (int rr = 0; rr < 4; ++rr) {
                int gr = gr0 + rr;
                float val = acc[i][j][rr] + bv;
                if (EPI == 0) {
                    ((u16*)outp)[(size_t)gr * N + gc] = f2bf(val);
                } else if (EPI == 1) {
                    float gl = val * 0.5f * (1.0f + erff(val * 0.70710678118654752f));
                    ((u16*)outp)[(size_t)gr * N + gc] = f2bf(gl);
                } else {
                    ((float*)outp)[(size_t)gr * N + gc] += val;
                }
            }
        }
    }
}

// ---- proj GEMM (full 192-col rows) + residual + FUSED LN2 epilogue -------
// r12-verified: deletes the LN2 dispatch. Single-pass E[x2]-E[x]2 row stats
// via 12-reg partials + 4 shfl_xor; writes out (f32) and h_buf (bf16 LN2).
__global__ __launch_bounds__(256) void proj_ln_kernel(
    const u16* __restrict__ A,       // att_buf bf16 [MROWS][192]
    const u16* __restrict__ W,       // proj_w bf16 [192][192]
    const float* __restrict__ bias,  // proj_b
    const float* __restrict__ xin,   // x f32
    float* __restrict__ out,         // x + attnproj (f32)
    const float* __restrict__ g2, const float* __restrict__ b2,
    u16* __restrict__ hout)          // h_buf bf16 = LN2(out)
{
    __shared__ u16 As[64 * 64];      // 8KB
    __shared__ u16 Bs[192 * 64];     // 24KB
    const int tid  = threadIdx.x;
    const int lane = tid & 63, wv = tid >> 6;
    const int ln16 = lane & 15, quad = lane >> 4;
    const int srow = lane >> 3;
    const int acol = ((lane & 7) ^ srow) * 8;

    const int flat = blockIdx.x;                 // grid 640, %8==0
    const int bm   = (flat & 7) * (gridDim.x >> 3) + (flat >> 3);

    f32x4 acc[12] = {};

    for (int k0 = 0; k0 < DIM; k0 += 64) {
        __syncthreads();
        #pragma unroll
        for (int a = 0; a < 2; ++a) {
            const u16* g = A + (size_t)(bm * 64 + a * 32 + wv * 8 + srow) * DIM + k0 + acol;
            __builtin_amdgcn_global_load_lds(
                (const __attribute__((address_space(1))) u32*)g,
                (__attribute__((address_space(3))) u32*)((char*)As + a * 4096 + wv * 1024),
                16, 0, 0);
        }
        #pragma unroll
        for (int bb = 0; bb < 6; ++bb) {
            const u16* g = W + (size_t)(bb * 32 + wv * 8 + srow) * DIM + k0 + acol;
            __builtin_amdgcn_global_load_lds(
                (const __attribute__((address_space(1))) u32*)g,
                (__attribute__((address_space(3))) u32*)((char*)Bs + bb * 4096 + wv * 1024),
                16, 0, 0);
        }
        __syncthreads();
        #pragma unroll
        for (int s = 0; s < 2; ++s) {
            int ra = wv * 16 + ln16;
            int slota = (s * 4 + quad) ^ (ra & 7);
            bf16x8 af = *(const bf16x8*)((const char*)As + ra * 128 + slota * 16);
            #pragma unroll
            for (int nt = 0; nt < 12; ++nt) {
                int r = nt * 16 + ln16;
                int slot = (s * 4 + quad) ^ (r & 7);
                bf16x8 bf = *(const bf16x8*)((const char*)Bs + r * 128 + slot * 16);
                acc[nt] = __builtin_amdgcn_mfma_f32_16x16x32_bf16(af, bf, acc[nt], 0, 0, 0);
            }
        }
    }

    const int gr0 = bm * 64 + wv * 16 + quad * 4;
    float s1[4] = {}, s2[4] = {};
    #pragma unroll
    for (int nt = 0; nt < 12; ++nt) {
        int gc = nt * 16 + ln16;
        float bv = bias[gc];
        #pragma unroll
        for (int rr = 0; rr < 4; ++rr) {
            size_t dst = (size_t)(gr0 + rr) * DIM + gc;
            float ov = xin[dst] + acc[nt][rr] + bv;
            out[dst] = ov;
            s1[rr] += ov;
            s2[rr] += ov * ov;
        }
    }
    #pragma unroll
    for (int rr = 0; rr < 4; ++rr) {
        #pragma unroll
        for (int off = 8; off; off >>= 1) {
            s1[rr] += __shfl_xor(s1[rr], off, 64);
            s2[rr] += __shfl_xor(s2[rr], off, 64);
        }
    }
    float mu[4], rstd[4];
    #pragma unroll
    for (int rr = 0; rr < 4; ++rr) {
        mu[rr] = s1[rr] * (1.0f / 192.0f);
        float var = s2[rr] * (1.0f / 192.0f) - mu[rr] * mu[rr];
        rstd[rr] = rsqrtf(var + 1e-5f);
    }
    #pragma unroll
    for (int nt = 0; nt < 12; ++nt) {
        int gc = nt * 16 + ln16;
        float bv = bias[gc];
        float gg = g2[gc], bb = b2[gc];
        #pragma unroll
        for (int rr = 0; rr < 4; ++rr) {
            size_t dst = (size_t)(gr0 + rr) * DIM + gc;
            float ov = xin[dst] + acc[nt][rr] + bv;
            hout[dst] = f2bf((ov - mu[rr]) * rstd[rr] * gg + bb);
        }
    }
}

// ---------------- MFMA flash attention: block = (window, head) ------------
// r14 K/V staging + softmax structure, but 10 WAVES per block (640 thr),
// each wave owning 2 q-tiles (32 rows) instead of 4. Rationale (r15
// falsification): the grid is 768 blocks = exactly 3 blocks/CU, so the
// residency cap is the GRID, not LDS -- freeing LDS (r15) changed nothing.
// Doubling waves *within* each block doubles waves/CU (15 -> 30) at the
// same 48.1KB LDS (3 blocks x 48.1 = 144KB < 160). Per-wave state halves
// (qf[2], o[2][2]) so VGPR drops. Threads 320..639 skip token staging.
// setprio removed (r14: null). Static-max exp2 softmax (r4-verified).
__global__ __launch_bounds__(640) void attn_kernel(
    const u16* __restrict__ qkv, const float* __restrict__ table,
    u16* __restrict__ attout)
{
    const int head = blockIdx.x % HEADS;
    const int b_   = blockIdx.x / HEADS;
    const int b = b_ >> 6, hb = (b_ >> 3) & 7, wb = b_ & 7;
    const int tid = threadIdx.x;
    const int lane = tid & 63, wv = tid >> 6;       // wv in 0..9
    const int ln16 = lane & 15, quad = lane >> 4;

    __shared__ u16 Ks[320 * 40];     // bf16, row pad 40 (16B-aligned rows)
    __shared__ u16 Vt[32 * 328];     // f16 transposed, row pad 328
    __shared__ u16 meta[320];        // off | (region<<8) per key token
    __shared__ float tbl[188];       // bias table pre-scaled by log2(e)

    // ---- staging: thread tid = window token n (tid < 320 only) ------------
    if (tid < 320) {
        int n = tid;
        int t1 = n >> 6, r1 = (n >> 3) & 7, c1 = n & 7;
        int h1 = hb * 8 + r1, w1 = wb * 8 + c1;
        int l1 = t1 * 4096 + ((h1 + 4) & 63) * 64 + ((w1 + 4) & 63);
        const u16* src = qkv + ((size_t)b * LTOK + l1) * (3 * DIM) + head * HD;
        const uint4* k4 = (const uint4*)(src + DIM);
        #pragma unroll
        for (int i = 0; i < 4; ++i)
            *(uint4*)(Ks + n * 40 + i * 8) = k4[i];
        const uint4* v4 = (const uint4*)(src + 2 * DIM);
        #pragma unroll
        for (int i = 0; i < 4; ++i) {
            uint4 u = v4[i];
            u32 ws[4] = {u.x, u.y, u.z, u.w};
            #pragma unroll
            for (int j = 0; j < 4; ++j) {
                u32 hb2 = pkh(bflo(ws[j]), bfhi(ws[j]));
                int d = i * 8 + j * 2;
                Vt[d * 328 + n]       = (u16)(hb2 & 0xFFFF);
                Vt[(d + 1) * 328 + n] = (u16)(hb2 >> 16);
            }
        }
        int off = (7 - t1) * 15 + 7 - r1 - c1;
        int rh = h1 < 56 ? 0 : (h1 < 60 ? 1 : 2);
        int rw = w1 < 56 ? 0 : (w1 < 60 ? 1 : 2);
        meta[n] = (u16)(off | ((rh * 3 + rw) << 8));
        if (n < 187) tbl[n] = table[n * HEADS + head] * LOG2E;
    }

    // ---- per-wave Q setup: 2 q-tiles of 16 rows (wave owns 32 rows) -------
    bf16x8 qf[2];
    int basen[2], myreg[2];
    #pragma unroll
    for (int qt = 0; qt < 2; ++qt) {
        int nq = wv * 32 + qt * 16 + ln16;
        int t1 = nq >> 6, r1 = (nq >> 3) & 7, c1 = nq & 7;
        int h1 = hb * 8 + r1, w1 = wb * 8 + c1;
        int l1 = t1 * 4096 + ((h1 + 4) & 63) * 64 + ((w1 + 4) & 63);
        qf[qt] = *(const bf16x8*)(qkv + ((size_t)b * LTOK + l1) * (3 * DIM)
                                  + head * HD + quad * 8);
        basen[qt] = t1 * 15 + r1 + c1;
        int rh = h1 < 56 ? 0 : (h1 < 60 ? 1 : 2);
        int rw = w1 < 56 ? 0 : (w1 < 60 ? 1 : 2);
        myreg[qt] = rh * 3 + rw;
    }

    __syncthreads();

    f32x4 o[2][2] = {};          // [qtile][d-half]: O^T rows=d(quad*4+r), col=qrow(ln16)
    float l_[2] = {};
    const f32x4 zero = {};

    #pragma unroll 1
    for (int c = 0; c < 10; ++c) {
        int kb = c * 32;
        bf16x8 af0 = *(const bf16x8*)(Ks + (kb + ln16) * 40 + quad * 8);
        bf16x8 af1 = *(const bf16x8*)(Ks + (kb + 16 + ln16) * 40 + quad * 8);
        f16x4 va[2][2];
        #pragma unroll
        for (int dt = 0; dt < 2; ++dt)
            #pragma unroll
            for (int kt = 0; kt < 2; ++kt)
                va[dt][kt] = *(const f16x4*)(Vt + (dt * 16 + ln16) * 328
                                             + kb + kt * 16 + quad * 4);
        ushort4 m4a = *(const ushort4*)(meta + kb + quad * 4);
        ushort4 m4b = *(const ushort4*)(meta + kb + 16 + quad * 4);
        u16 mta[4] = {m4a.x, m4a.y, m4a.z, m4a.w};
        u16 mtb[4] = {m4b.x, m4b.y, m4b.z, m4b.w};

        #pragma unroll
        for (int qt = 0; qt < 2; ++qt) {
            f32x4 s0 = __builtin_amdgcn_mfma_f32_16x16x32_bf16(af0, qf[qt], zero, 0, 0, 0);
            f32x4 s1 = __builtin_amdgcn_mfma_f32_16x16x32_bf16(af1, qf[qt], zero, 0, 0, 0);
            float p[8];
            #pragma unroll
            for (int r = 0; r < 4; ++r) {
                int ma = mta[r], mb = mtb[r];
                float va0 = fmaf(s0[r], QSCALE2, tbl[basen[qt] + (ma & 0xFF)]);
                float vb0 = fmaf(s1[r], QSCALE2, tbl[basen[qt] + (mb & 0xFF)]);
                p[r]     = va0 + (((ma >> 8) == myreg[qt]) ? 0.0f : MASK2);
                p[4 + r] = vb0 + (((mb >> 8) == myreg[qt]) ? 0.0f : MASK2);
            }
            float ls = 0.0f;
            #pragma unroll
            for (int j = 0; j < 8; ++j) { p[j] = ex2(p[j]); ls += p[j]; }
            l_[qt] += ls;
            uint2 pk0 = { pkh(p[0], p[1]), pkh(p[2], p[3]) };
            uint2 pk1 = { pkh(p[4], p[5]), pkh(p[6], p[7]) };
            f16x4 pf0 = __builtin_bit_cast(f16x4, pk0);
            f16x4 pf1 = __builtin_bit_cast(f16x4, pk1);
            #pragma unroll
            for (int dt = 0; dt < 2; ++dt) {
                o[qt][dt] = __builtin_amdgcn_mfma_f32_16x16x16f16(va[dt][0], pf0, o[qt][dt], 0, 0, 0);
                o[qt][dt] = __builtin_amdgcn_mfma_f32_16x16x16f16(va[dt][1], pf1, o[qt][dt], 0, 0, 0);
            }
        }
    }

    // ---- epilogue: normalize, pack bf16, store O (token-major) ------------
    #pragma unroll
    for (int qt = 0; qt < 2; ++qt) {
        float lt = l_[qt];
        lt += __shfl_xor(lt, 16, 64);
        lt += __shfl_xor(lt, 32, 64);
        float inv = 1.0f / lt;
        int nq = wv * 32 + qt * 16 + ln16;
        u16* dst = attout + ((size_t)(b_ * NWIN + nq)) * DIM + head * HD + quad * 4;
        #pragma unroll
        for (int dt = 0; dt < 2; ++dt) {
            u32 w0 = (u32)f2bf(o[qt][dt][0] * inv) | ((u32)f2bf(o[qt][dt][1] * inv) << 16);
            u32 w1 = (u32)f2bf(o[qt][dt][2] * inv) | ((u32)f2bf(o[qt][dt][3] * inv) << 16);
            uint2 st = {w0, w1};
            *(uint2*)(dst + dt * 16) = st;
        }
    }
}

// ---------------------------------------------------------------------------
extern "C" void kernel_launch(void* const* d_in, const int* in_sizes, int n_in,
                              void* d_out, int out_size, void* d_ws, size_t ws_size,
                              hipStream_t stream)
{
    (void)in_sizes; (void)n_in; (void)out_size; (void)ws_size;
    const float* x      = (const float*)d_in[0];
    const float* ln1_g  = (const float*)d_in[1];
    const float* ln1_b  = (const float*)d_in[2];
    const float* qkv_w  = (const float*)d_in[3];
    const float* qkv_b  = (const float*)d_in[4];
    const float* table  = (const float*)d_in[5];
    const float* proj_w = (const float*)d_in[6];
    const float* proj_b = (const float*)d_in[7];
    const float* ln2_g  = (const float*)d_in[8];
    const float* ln2_b  = (const float*)d_in[9];
    const float* fc1_w  = (const float*)d_in[10];
    const float* fc1_b  = (const float*)d_in[11];
    const float* fc2_w  = (const float*)d_in[12];
    const float* fc2_b  = (const float*)d_in[13];
    float* out = (float*)d_out;

    u16* wsu     = (u16*)d_ws;
    u16* h_buf   = wsu;
    u16* qkv_buf = wsu + (size_t)MROWS * DIM;
    u16* att_buf = wsu + (size_t)MROWS * (4 * DIM);
    u16* fc1_buf = wsu + (size_t)MROWS * DIM;
    u16* wq = wsu + (size_t)MROWS * (5 * DIM);
    u16* wp = wq + 3 * DIM * DIM;
    u16* w1 = wp + DIM * DIM;
    u16* w2 = w1 + 4 * DIM * DIM;

    prep_kernel<<<CVT_BLOCKS + MROWS / 4, 256, 0, stream>>>(
        x, ln1_g, ln1_b, h_buf,
        qkv_w, proj_w, fc1_w, fc2_w, wq, wp, w1, w2);

    mfma_gemm<0, 128><<<dim3(3 * DIM / 64, MROWS / 128), 256, 0, stream>>>(
        h_buf, wq, qkv_b, qkv_buf, nullptr, 3 * DIM, DIM);
    attn_kernel<<<128 * HEADS, 640, 0, stream>>>(qkv_buf, table, att_buf);
    proj_ln_kernel<<<MROWS / 64, 256, 0, stream>>>(
        att_buf, wp, proj_b, x, out, ln2_g, ln2_b, h_buf);
    mfma_gemm<1, 128><<<dim3(4 * DIM / 64, MROWS / 128), 256, 0, stream>>>(
        h_buf, w1, fc1_b, fc1_buf, nullptr, 4 * DIM, DIM);
    mfma_gemm<3, 64><<<dim3(DIM / 64, MROWS / 64), 256, 0, stream>>>(
        fc1_buf, w2, fc2_b, out, nullptr, DIM, 4 * DIM);
}

// Round 17
// 244.354 us; speedup vs baseline: 1.0360x; 1.0117x over previous
//
#include <hip/hip_runtime.h>
#include <math.h>

typedef unsigned short u16;
typedef unsigned int u32;
typedef short bf16x8 __attribute__((ext_vector_type(8)));
typedef float f32x4 __attribute__((ext_vector_type(4)));
typedef _Float16 f16x4 __attribute__((ext_vector_type(4)));

#define TT 5
#define HEADS 6
#define HD 32
#define DIM 192
#define NWIN 320              // tokens per window = T*8*8
#define LTOK (TT*64*64)       // 20480
#define BATCH 2
#define MROWS (BATCH*LTOK)    // 40960
#define QSCALE 0.17677669529663687f   // 1/sqrt(32)
#define LOG2E 1.4426950408889634f
#define QSCALE2 (QSCALE * LOG2E)
#define MASK2 (-100.0f * LOG2E)       // -144.2695: 2^x -> 0
#define CVT_BLOCKS 1728               // 12*DIM*DIM/256

__device__ __forceinline__ u16 f2bf(float f) {
    u32 u = __float_as_uint(f);
    u32 r = (u + 0x7FFFu + ((u >> 16) & 1u)) >> 16;
    return (u16)r;
}
__device__ __forceinline__ float bflo(u32 u) { return __uint_as_float(u << 16); }
__device__ __forceinline__ float bfhi(u32 u) { return __uint_as_float(u & 0xFFFF0000u); }
__device__ __forceinline__ u32 pkh(float a, float b) {
    auto h = __builtin_amdgcn_cvt_pkrtz(a, b);
    return __builtin_bit_cast(u32, h);
}
#if __has_builtin(__builtin_amdgcn_exp2f)
__device__ __forceinline__ float ex2(float x) { return __builtin_amdgcn_exp2f(x); }
#else
__device__ __forceinline__ float ex2(float x) {
    float r; asm("v_exp_f32 %0, %1" : "=v"(r) : "v"(x)); return r;
}
#endif
// tanh-form GELU in exp2 domain: x*sigmoid(1.5958*(x+0.044715x^3)).
// t = 2^(2.302208*u) = e^(2z); gl = x - x*rcp(1+t)  (inf-safe, ~1e-3 abs err)
__device__ __forceinline__ float gelu_fast(float x) {
    float u = fmaf(0.044715f * x * x, x, x);
    float t = ex2(2.302208f * u);
    return x - x * __builtin_amdgcn_rcpf(1.0f + t);
}

// ---- prep: weight cvt (blocks 0..1727) + LN1 (remaining blocks) ----------
__global__ __launch_bounds__(256) void prep_kernel(
    const float* __restrict__ x, const float* __restrict__ g,
    const float* __restrict__ b, u16* __restrict__ out,
    const float* __restrict__ wa, const float* __restrict__ wb,
    const float* __restrict__ wc, const float* __restrict__ wd,
    u16* __restrict__ oa, u16* __restrict__ ob,
    u16* __restrict__ oc, u16* __restrict__ od)
{
    if (blockIdx.x < CVT_BLOCKS) {
        int i = blockIdx.x * 256 + threadIdx.x;
        if (i < 110592)       oa[i]          = f2bf(wa[i]);           // qkv_w
        else if (i < 147456)  ob[i - 110592] = f2bf(wb[i - 110592]);  // proj_w
        else if (i < 294912)  oc[i - 147456] = f2bf(wc[i - 147456]);  // fc1_w
        else                  od[i - 294912] = f2bf(wd[i - 294912]);  // fc2_w
        return;
    }
    int tok  = (blockIdx.x - CVT_BLOCKS) * 4 + (threadIdx.x >> 6);
    int lane = threadIdx.x & 63;
    const float* xr = x + (size_t)tok * DIM;
    float v0 = xr[lane], v1 = xr[lane + 64], v2 = xr[lane + 128];
    float s = v0 + v1 + v2;
    #pragma unroll
    for (int off = 32; off; off >>= 1) s += __shfl_xor(s, off, 64);
    float mu = s * (1.0f / 192.0f);
    float d0 = v0 - mu, d1 = v1 - mu, d2 = v2 - mu;
    float vs = d0 * d0 + d1 * d1 + d2 * d2;
    #pragma unroll
    for (int off = 32; off; off >>= 1) vs += __shfl_xor(vs, off, 64);
    float rstd = rsqrtf(vs * (1.0f / 192.0f) + 1e-5f);
    u16* orow = out + (size_t)tok * DIM;
    orow[lane]       = f2bf(d0 * rstd * g[lane]       + b[lane]);
    orow[lane + 64]  = f2bf(d1 * rstd * g[lane + 64]  + b[lane + 64]);
    orow[lane + 128] = f2bf(d2 * rstd * g[lane + 128] + b[lane + 128]);
}

// ---------------- bf16 MFMA GEMM: C = A(MxK) @ W(NxK)^T + bias ------------
// r4 structure (single-buffer staged loop + XCD swizzle). History: r5 dbuf /
// r7 direct-A / r8 hoist / r11 fused-MLP all regressed; r13: BM=64 on
// grid-filled GEMMs per-se neutral. Config per r12 best: qkv/fc1 128, fc2 64.
// r17: EPI=1 GELU switched from erff (~25-30 VALU) to tanh-form gelu_fast
// (~8 VALU) -- fc1's VALUBusy was 41% with the erf epilogue on 31.5M outputs.
template<int EPI, int BM>
__global__ __launch_bounds__(256) void mfma_gemm(
    const u16* __restrict__ A, const u16* __restrict__ W,
    const float* __restrict__ bias, void* __restrict__ outp,
    const float* __restrict__ xin, int N, int K)
{
    constexpr int WR = BM / 64;     // 16-row tiles per wave
    constexpr int NA = BM / 32;     // A-stage chunks per K-step
    __shared__ u16 As[BM * 64];
    __shared__ u16 Bs[64 * 64];
    const int tid  = threadIdx.x;
    const int lane = tid & 63, wv = tid >> 6;
    const int ln16 = lane & 15, quad = lane >> 4;

    const int flat  = blockIdx.y * gridDim.x + blockIdx.x;
    const int cpx   = (gridDim.x * gridDim.y) >> 3;
    const int nf    = (flat & 7) * cpx + (flat >> 3);
    const int bn    = nf % gridDim.x;
    const int bm    = nf / gridDim.x;

    const int srow = lane >> 3;
    const int sxor = (lane & 7) ^ srow;
    const int acol = sxor * 8;

    f32x4 acc[WR][4] = {};

    for (int k0 = 0; k0 < K; k0 += 64) {
        __syncthreads();
        #pragma unroll
        for (int a = 0; a < NA; ++a) {
            const u16* g = A + (size_t)(bm * BM + a * 32 + wv * 8 + srow) * K + k0 + acol;
            __builtin_amdgcn_global_load_lds(
                (const __attribute__((address_space(1))) u32*)g,
                (__attribute__((address_space(3))) u32*)((char*)As + a * 4096 + wv * 1024),
                16, 0, 0);
        }
        #pragma unroll
        for (int bb = 0; bb < 2; ++bb) {
            const u16* g = W + (size_t)(bn * 64 + bb * 32 + wv * 8 + srow) * K + k0 + acol;
            __builtin_amdgcn_global_load_lds(
                (const __attribute__((address_space(1))) u32*)g,
                (__attribute__((address_space(3))) u32*)((char*)Bs + bb * 4096 + wv * 1024),
                16, 0, 0);
        }
        __syncthreads();
        #pragma unroll
        for (int s = 0; s < 2; ++s) {
            bf16x8 af[WR], bf[4];
            #pragma unroll
            for (int i = 0; i < WR; ++i) {
                int r = wv * (16 * WR) + i * 16 + ln16;
                int slot = (s * 4 + quad) ^ (r & 7);
                af[i] = *(const bf16x8*)((const char*)As + r * 128 + slot * 16);
            }
            #pragma unroll
            for (int j = 0; j < 4; ++j) {
                int r = j * 16 + ln16;
                int slot = (s * 4 + quad) ^ (r & 7);
                bf[j] = *(const bf16x8*)((const char*)Bs + r * 128 + slot * 16);
            }
            #pragma unroll
            for (int i = 0; i < WR; ++i)
                #pragma unroll
                for (int j = 0; j < 4; ++j)
                    acc[i][j] = __builtin_amdgcn_mfma_f32_16x16x32_bf16(
                        af[i], bf[j], acc[i][j], 0, 0, 0);
        }
    }

    #pragma unroll
    for (int i = 0; i < WR; ++i) {
        int gr0 = bm * BM + wv * (16 * WR) + i * 16 + quad * 4;
        #pragma unroll
        for (int j = 0; j < 4; ++j) {
            int gc = bn * 64 + j * 16 + ln16;
            float bv = bias[gc];
            #pragma unroll
            for (int rr = 0; rr < 4; ++rr) {
                int gr = gr0 + rr;
                float val = acc[i][j][rr] + bv;
                if (EPI == 0) {
                    ((u16*)outp)[(size_t)gr * N + gc] = f2bf(val);
                } else if (EPI == 1) {
                    ((u16*)outp)[(size_t)gr * N + gc] = f2bf(gelu_fast(val));
                } else {
                    ((float*)outp)[(size_t)gr * N + gc] += val;
                }
            }
        }
    }
}

// ---- proj GEMM (full 192-col rows) + residual + FUSED LN2 epilogue -------
// r12-verified: deletes the LN2 dispatch. Single-pass E[x2]-E[x]2 row stats
// via 12-reg partials + 4 shfl_xor; writes out (f32) and h_buf (bf16 LN2).
__global__ __launch_bounds__(256) void proj_ln_kernel(
    const u16* __restrict__ A,       // att_buf bf16 [MROWS][192]
    const u16* __restrict__ W,       // proj_w bf16 [192][192]
    const float* __restrict__ bias,  // proj_b
    const float* __restrict__ xin,   // x f32
    float* __restrict__ out,         // x + attnproj (f32)
    const float* __restrict__ g2, const float* __restrict__ b2,
    u16* __restrict__ hout)          // h_buf bf16 = LN2(out)
{
    __shared__ u16 As[64 * 64];      // 8KB
    __shared__ u16 Bs[192 * 64];     // 24KB
    const int tid  = threadIdx.x;
    const int lane = tid & 63, wv = tid >> 6;
    const int ln16 = lane & 15, quad = lane >> 4;
    const int srow = lane >> 3;
    const int acol = ((lane & 7) ^ srow) * 8;

    const int flat = blockIdx.x;                 // grid 640, %8==0
    const int bm   = (flat & 7) * (gridDim.x >> 3) + (flat >> 3);

    f32x4 acc[12] = {};

    for (int k0 = 0; k0 < DIM; k0 += 64) {
        __syncthreads();
        #pragma unroll
        for (int a = 0; a < 2; ++a) {
            const u16* g = A + (size_t)(bm * 64 + a * 32 + wv * 8 + srow) * DIM + k0 + acol;
            __builtin_amdgcn_global_load_lds(
                (const __attribute__((address_space(1))) u32*)g,
                (__attribute__((address_space(3))) u32*)((char*)As + a * 4096 + wv * 1024),
                16, 0, 0);
        }
        #pragma unroll
        for (int bb = 0; bb < 6; ++bb) {
            const u16* g = W + (size_t)(bb * 32 + wv * 8 + srow) * DIM + k0 + acol;
            __builtin_amdgcn_global_load_lds(
                (const __attribute__((address_space(1))) u32*)g,
                (__attribute__((address_space(3))) u32*)((char*)Bs + bb * 4096 + wv * 1024),
                16, 0, 0);
        }
        __syncthreads();
        #pragma unroll
        for (int s = 0; s < 2; ++s) {
            int ra = wv * 16 + ln16;
            int slota = (s * 4 + quad) ^ (ra & 7);
            bf16x8 af = *(const bf16x8*)((const char*)As + ra * 128 + slota * 16);
            #pragma unroll
            for (int nt = 0; nt < 12; ++nt) {
                int r = nt * 16 + ln16;
                int slot = (s * 4 + quad) ^ (r & 7);
                bf16x8 bf = *(const bf16x8*)((const char*)Bs + r * 128 + slot * 16);
                acc[nt] = __builtin_amdgcn_mfma_f32_16x16x32_bf16(af, bf, acc[nt], 0, 0, 0);
            }
        }
    }

    const int gr0 = bm * 64 + wv * 16 + quad * 4;
    float s1[4] = {}, s2[4] = {};
    #pragma unroll
    for (int nt = 0; nt < 12; ++nt) {
        int gc = nt * 16 + ln16;
        float bv = bias[gc];
        #pragma unroll
        for (int rr = 0; rr < 4; ++rr) {
            size_t dst = (size_t)(gr0 + rr) * DIM + gc;
            float ov = xin[dst] + acc[nt][rr] + bv;
            out[dst] = ov;
            s1[rr] += ov;
            s2[rr] += ov * ov;
        }
    }
    #pragma unroll
    for (int rr = 0; rr < 4; ++rr) {
        #pragma unroll
        for (int off = 8; off; off >>= 1) {
            s1[rr] += __shfl_xor(s1[rr], off, 64);
            s2[rr] += __shfl_xor(s2[rr], off, 64);
        }
    }
    float mu[4], rstd[4];
    #pragma unroll
    for (int rr = 0; rr < 4; ++rr) {
        mu[rr] = s1[rr] * (1.0f / 192.0f);
        float var = s2[rr] * (1.0f / 192.0f) - mu[rr] * mu[rr];
        rstd[rr] = rsqrtf(var + 1e-5f);
    }
    #pragma unroll
    for (int nt = 0; nt < 12; ++nt) {
        int gc = nt * 16 + ln16;
        float bv = bias[gc];
        float gg = g2[gc], bb = b2[gc];
        #pragma unroll
        for (int rr = 0; rr < 4; ++rr) {
            size_t dst = (size_t)(gr0 + rr) * DIM + gc;
            float ov = xin[dst] + acc[nt][rr] + bv;
            hout[dst] = f2bf((ov - mu[rr]) * rstd[rr] * gg + bb);
        }
    }
}

// ---------------- MFMA flash attention: block = (window, head) ------------
// r16-verified: 10 waves/block (640 thr), each wave owns 2 q-tiles; grid is
// 768 blocks = 3 blocks/CU (grid-capped), so 10 waves/block gives 30
// waves/CU at the same 48.1KB LDS. Static-max exp2 softmax (r4-verified).
__global__ __launch_bounds__(640) void attn_kernel(
    const u16* __restrict__ qkv, const float* __restrict__ table,
    u16* __restrict__ attout)
{
    const int head = blockIdx.x % HEADS;
    const int b_   = blockIdx.x / HEADS;
    const int b = b_ >> 6, hb = (b_ >> 3) & 7, wb = b_ & 7;
    const int tid = threadIdx.x;
    const int lane = tid & 63, wv = tid >> 6;       // wv in 0..9
    const int ln16 = lane & 15, quad = lane >> 4;

    __shared__ u16 Ks[320 * 40];     // bf16, row pad 40 (16B-aligned rows)
    __shared__ u16 Vt[32 * 328];     // f16 transposed, row pad 328
    __shared__ u16 meta[320];        // off | (region<<8) per key token
    __shared__ float tbl[188];       // bias table pre-scaled by log2(e)

    if (tid < 320) {
        int n = tid;
        int t1 = n >> 6, r1 = (n >> 3) & 7, c1 = n & 7;
        int h1 = hb * 8 + r1, w1 = wb * 8 + c1;
        int l1 = t1 * 4096 + ((h1 + 4) & 63) * 64 + ((w1 + 4) & 63);
        const u16* src = qkv + ((size_t)b * LTOK + l1) * (3 * DIM) + head * HD;
        const uint4* k4 = (const uint4*)(src + DIM);
        #pragma unroll
        for (int i = 0; i < 4; ++i)
            *(uint4*)(Ks + n * 40 + i * 8) = k4[i];
        const uint4* v4 = (const uint4*)(src + 2 * DIM);
        #pragma unroll
        for (int i = 0; i < 4; ++i) {
            uint4 u = v4[i];
            u32 ws[4] = {u.x, u.y, u.z, u.w};
            #pragma unroll
            for (int j = 0; j < 4; ++j) {
                u32 hb2 = pkh(bflo(ws[j]), bfhi(ws[j]));
                int d = i * 8 + j * 2;
                Vt[d * 328 + n]       = (u16)(hb2 & 0xFFFF);
                Vt[(d + 1) * 328 + n] = (u16)(hb2 >> 16);
            }
        }
        int off = (7 - t1) * 15 + 7 - r1 - c1;
        int rh = h1 < 56 ? 0 : (h1 < 60 ? 1 : 2);
        int rw = w1 < 56 ? 0 : (w1 < 60 ? 1 : 2);
        meta[n] = (u16)(off | ((rh * 3 + rw) << 8));
        if (n < 187) tbl[n] = table[n * HEADS + head] * LOG2E;
    }

    bf16x8 qf[2];
    int basen[2], myreg[2];
    #pragma unroll
    for (int qt = 0; qt < 2; ++qt) {
        int nq = wv * 32 + qt * 16 + ln16;
        int t1 = nq >> 6, r1 = (nq >> 3) & 7, c1 = nq & 7;
        int h1 = hb * 8 + r1, w1 = wb * 8 + c1;
        int l1 = t1 * 4096 + ((h1 + 4) & 63) * 64 + ((w1 + 4) & 63);
        qf[qt] = *(const bf16x8*)(qkv + ((size_t)b * LTOK + l1) * (3 * DIM)
                                  + head * HD + quad * 8);
        basen[qt] = t1 * 15 + r1 + c1;
        int rh = h1 < 56 ? 0 : (h1 < 60 ? 1 : 2);
        int rw = w1 < 56 ? 0 : (w1 < 60 ? 1 : 2);
        myreg[qt] = rh * 3 + rw;
    }

    __syncthreads();

    f32x4 o[2][2] = {};
    float l_[2] = {};
    const f32x4 zero = {};

    #pragma unroll 1
    for (int c = 0; c < 10; ++c) {
        int kb = c * 32;
        bf16x8 af0 = *(const bf16x8*)(Ks + (kb + ln16) * 40 + quad * 8);
        bf16x8 af1 = *(const bf16x8*)(Ks + (kb + 16 + ln16) * 40 + quad * 8);
        f16x4 va[2][2];
        #pragma unroll
        for (int dt = 0; dt < 2; ++dt)
            #pragma unroll
            for (int kt = 0; kt < 2; ++kt)
                va[dt][kt] = *(const f16x4*)(Vt + (dt * 16 + ln16) * 328
                                             + kb + kt * 16 + quad * 4);
        ushort4 m4a = *(const ushort4*)(meta + kb + quad * 4);
        ushort4 m4b = *(const ushort4*)(meta + kb + 16 + quad * 4);
        u16 mta[4] = {m4a.x, m4a.y, m4a.z, m4a.w};
        u16 mtb[4] = {m4b.x, m4b.y, m4b.z, m4b.w};

        #pragma unroll
        for (int qt = 0; qt < 2; ++qt) {
            f32x4 s0 = __builtin_amdgcn_mfma_f32_16x16x32_bf16(af0, qf[qt], zero, 0, 0, 0);
            f32x4 s1 = __builtin_amdgcn_mfma_f32_16x16x32_bf16(af1, qf[qt], zero, 0, 0, 0);
            float p[8];
            #pragma unroll
            for (int r = 0; r < 4; ++r) {
                int ma = mta[r], mb = mtb[r];
                float va0 = fmaf(s0[r], QSCALE2, tbl[basen[qt] + (ma & 0xFF)]);
                float vb0 = fmaf(s1[r], QSCALE2, tbl[basen[qt] + (mb & 0xFF)]);
                p[r]     = va0 + (((ma >> 8) == myreg[qt]) ? 0.0f : MASK2);
                p[4 + r] = vb0 + (((mb >> 8) == myreg[qt]) ? 0.0f : MASK2);
            }
            float ls = 0.0f;
            #pragma unroll
            for (int j = 0; j < 8; ++j) { p[j] = ex2(p[j]); ls += p[j]; }
            l_[qt] += ls;
            uint2 pk0 = { pkh(p[0], p[1]), pkh(p[2], p[3]) };
            uint2 pk1 = { pkh(p[4], p[5]), pkh(p[6], p[7]) };
            f16x4 pf0 = __builtin_bit_cast(f16x4, pk0);
            f16x4 pf1 = __builtin_bit_cast(f16x4, pk1);
            #pragma unroll
            for (int dt = 0; dt < 2; ++dt) {
                o[qt][dt] = __builtin_amdgcn_mfma_f32_16x16x16f16(va[dt][0], pf0, o[qt][dt], 0, 0, 0);
                o[qt][dt] = __builtin_amdgcn_mfma_f32_16x16x16f16(va[dt][1], pf1, o[qt][dt], 0, 0, 0);
            }
        }
    }

    #pragma unroll
    for (int qt = 0; qt < 2; ++qt) {
        float lt = l_[qt];
        lt += __shfl_xor(lt, 16, 64);
        lt += __shfl_xor(lt, 32, 64);
        float inv = 1.0f / lt;
        int nq = wv * 32 + qt * 16 + ln16;
        u16* dst = attout + ((size_t)(b_ * NWIN + nq)) * DIM + head * HD + quad * 4;
        #pragma unroll
        for (int dt = 0; dt < 2; ++dt) {
            u32 w0 = (u32)f2bf(o[qt][dt][0] * inv) | ((u32)f2bf(o[qt][dt][1] * inv) << 16);
            u32 w1 = (u32)f2bf(o[qt][dt][2] * inv) | ((u32)f2bf(o[qt][dt][3] * inv) << 16);
            uint2 st = {w0, w1};
            *(uint2*)(dst + dt * 16) = st;
        }
    }
}

// ---------------------------------------------------------------------------
extern "C" void kernel_launch(void* const* d_in, const int* in_sizes, int n_in,
                              void* d_out, int out_size, void* d_ws, size_t ws_size,
                              hipStream_t stream)
{
    (void)in_sizes; (void)n_in; (void)out_size; (void)ws_size;
    const float* x      = (const float*)d_in[0];
    const float* ln1_g  = (const float*)d_in[1];
    const float* ln1_b  = (const float*)d_in[2];
    const float* qkv_w  = (const float*)d_in[3];
    const float* qkv_b  = (const float*)d_in[4];
    const float* table  = (const float*)d_in[5];
    const float* proj_w = (const float*)d_in[6];
    const float* proj_b = (const float*)d_in[7];
    const float* ln2_g  = (const float*)d_in[8];
    const float* ln2_b  = (const float*)d_in[9];
    const float* fc1_w  = (const float*)d_in[10];
    const float* fc1_b  = (const float*)d_in[11];
    const float* fc2_w  = (const float*)d_in[12];
    const float* fc2_b  = (const float*)d_in[13];
    float* out = (float*)d_out;

    u16* wsu     = (u16*)d_ws;
    u16* h_buf   = wsu;
    u16* qkv_buf = wsu + (size_t)MROWS * DIM;
    u16* att_buf = wsu + (size_t)MROWS * (4 * DIM);
    u16* fc1_buf = wsu + (size_t)MROWS * DIM;
    u16* wq = wsu + (size_t)MROWS * (5 * DIM);
    u16* wp = wq + 3 * DIM * DIM;
    u16* w1 = wp + DIM * DIM;
    u16* w2 = w1 + 4 * DIM * DIM;

    prep_kernel<<<CVT_BLOCKS + MROWS / 4, 256, 0, stream>>>(
        x, ln1_g, ln1_b, h_buf,
        qkv_w, proj_w, fc1_w, fc2_w, wq, wp, w1, w2);

    mfma_gemm<0, 128><<<dim3(3 * DIM / 64, MROWS / 128), 256, 0, stream>>>(
        h_buf, wq, qkv_b, qkv_buf, nullptr, 3 * DIM, DIM);
    attn_kernel<<<128 * HEADS, 640, 0, stream>>>(qkv_buf, table, att_buf);
    proj_ln_kernel<<<MROWS / 64, 256, 0, stream>>>(
        att_buf, wp, proj_b, x, out, ln2_g, ln2_b, h_buf);
    mfma_gemm<1, 128><<<dim3(4 * DIM / 64, MROWS / 128), 256, 0, stream>>>(
        h_buf, w1, fc1_b, fc1_buf, nullptr, 4 * DIM, DIM);
    mfma_gemm<3, 64><<<dim3(DIM / 64, MROWS / 64), 256, 0, stream>>>(
        fc1_buf, w2, fc2_b, out, nullptr, DIM, 4 * DIM);
}